// Round 1
// baseline (12988.069 us; speedup 1.0000x reference)
//
#include <hip/hip_runtime.h>
#include <math.h>

// ---- problem constants ----
#define Bn 32
#define Sn 197
#define Dn 768
#define Hn 12
#define DHn 64
#define Fn 3072
#define Ln 12
#define NPATCH 196
#define NCLSn 1000
#define MTOK (Bn * Sn)   // 6304

typedef __attribute__((ext_vector_type(8))) short short8;
typedef __attribute__((ext_vector_type(4))) float f32x4;

__device__ __forceinline__ unsigned short f2bf(float f) {
  union { float f; unsigned int u; } v; v.f = f;
  unsigned int r = v.u + 0x7fffu + ((v.u >> 16) & 1u);
  return (unsigned short)(r >> 16);
}
__device__ __forceinline__ float bf2f(unsigned short h) {
  union { unsigned int u; float f; } v; v.u = ((unsigned int)h) << 16;
  return v.f;
}

// ---- transpose + cast fp32[rows][cols] -> bf16[cols][rows] ----
__global__ __launch_bounds__(256) void transpose_cast(
    const float* __restrict__ in, unsigned short* __restrict__ out,
    int rows, int cols) {
  __shared__ float tile[32][33];
  int c0 = blockIdx.x * 32, r0 = blockIdx.y * 32;
  int tx = threadIdx.x, ty = threadIdx.y;
  for (int i = 0; i < 32; i += 8) {
    int r = r0 + ty + i, c = c0 + tx;
    tile[ty + i][tx] = (r < rows && c < cols) ? in[(size_t)r * cols + c] : 0.f;
  }
  __syncthreads();
  for (int i = 0; i < 32; i += 8) {
    int c = c0 + ty + i, r = r0 + tx;
    if (c < cols && r < rows)
      out[(size_t)c * rows + r] = f2bf(tile[tx][ty + i]);
  }
}

// ---- plain cast fp32 -> bf16 ----
__global__ __launch_bounds__(256) void cast_bf(
    const float* __restrict__ in, unsigned short* __restrict__ out, int n) {
  int i = blockIdx.x * 256 + threadIdx.x;
  if (i < n) out[i] = f2bf(in[i]);
}

// ---- im2col: X[B,3,224,224] -> A[b*196+hp*14+wp][c*256+p*16+q] bf16 ----
__global__ __launch_bounds__(256) void im2col_patches(
    const float* __restrict__ X, unsigned short* __restrict__ A) {
  int idx = blockIdx.x * 256 + threadIdx.x;
  if (idx >= NPATCH * Bn * Dn) return;
  int col = idx % Dn, row = idx / Dn;
  int b = row / NPATCH, pi = row % NPATCH;
  int hp = pi / 14, wp = pi % 14;
  int c = col >> 8, r2 = col & 255, p = r2 >> 4, q = r2 & 15;
  A[idx] = f2bf(X[(((size_t)b * 3 + c) * 224 + hp * 16 + p) * 224 + wp * 16 + q]);
}

// ---- x[b][0][:] = cls_token + pos_emb[0] ----
__global__ __launch_bounds__(256) void init_cls(
    const float* __restrict__ cls_tok, const float* __restrict__ pos_emb,
    float* __restrict__ x) {
  int i = blockIdx.x * 256 + threadIdx.x;
  if (i >= Bn * Dn) return;
  int b = i / Dn, d = i % Dn;
  x[(size_t)b * Sn * Dn + d] = cls_tok[d] + pos_emb[d];
}

// ---- LayerNorm over D=768; out bf16 ----
__global__ __launch_bounds__(256) void layernorm_k(
    const float* __restrict__ x, int row_stride,
    const float* __restrict__ g, const float* __restrict__ b,
    unsigned short* __restrict__ out) {
  int row = blockIdx.x, t = threadIdx.x;
  const float* xr = x + (size_t)row * row_stride;
  float v0 = xr[t], v1 = xr[t + 256], v2 = xr[t + 512];
  float s = v0 + v1 + v2;
  __shared__ float red[4];
  int lane = t & 63, wid = t >> 6;
  for (int off = 32; off > 0; off >>= 1) s += __shfl_xor(s, off, 64);
  if (lane == 0) red[wid] = s;
  __syncthreads();
  float mean = (red[0] + red[1] + red[2] + red[3]) * (1.f / 768.f);
  __syncthreads();
  float d0 = v0 - mean, d1 = v1 - mean, d2 = v2 - mean;
  float q = d0 * d0 + d1 * d1 + d2 * d2;
  for (int off = 32; off > 0; off >>= 1) q += __shfl_xor(q, off, 64);
  if (lane == 0) red[wid] = q;
  __syncthreads();
  float var = (red[0] + red[1] + red[2] + red[3]) * (1.f / 768.f);
  float rstd = rsqrtf(var + 1e-5f);
  size_t o = (size_t)row * Dn;
  out[o + t]       = f2bf(d0 * rstd * g[t]       + b[t]);
  out[o + t + 256] = f2bf(d1 * rstd * g[t + 256] + b[t + 256]);
  out[o + t + 512] = f2bf(d2 * rstd * g[t + 512] + b[t + 512]);
}

// ---- MFMA GEMM: C[M][N] = A[M][K](bf16) * Bt[N][K](bf16)^T, fused epilogues ----
// MODE 0: out bf16 qkv [B][H][S][DH]        (bias)
// MODE 1: out fp32 [M][N] = acc+bias+res    (residual add, in-place on x ok)
// MODE 2: out bf16 [M][N] = gelu(acc+bias)
// MODE 3: patch: out fp32 x[b][1+pi][n] = acc+bias+pos_emb[(1+pi)*D+n]
// MODE 4: out fp32 [M][N] = acc+bias
template <int MODE>
__global__ __launch_bounds__(256) void gemm64(
    const unsigned short* __restrict__ A, const unsigned short* __restrict__ Bt,
    const float* __restrict__ bias, const float* __restrict__ res,
    float* __restrict__ Cf, unsigned short* __restrict__ Cb,
    int M, int N, int K) {
  __shared__ unsigned short As[64][32];
  __shared__ unsigned short Bs[64][32];
  int m0 = blockIdx.x * 64, n0 = blockIdx.y * 64;
  int tid = threadIdx.x;
  int wid = tid >> 6, lane = tid & 63;
  int wm = (wid >> 1) * 32, wn = (wid & 1) * 32;
  int lrow = lane & 15, lq = lane >> 4;
  int lr = tid >> 2, lseg = (tid & 3) * 8;
  f32x4 acc[2][2] = {};
  for (int k0 = 0; k0 < K; k0 += 32) {
    int gm = m0 + lr;
    uint4 av = (gm < M) ? *(const uint4*)(A + (size_t)gm * K + k0 + lseg)
                        : make_uint4(0, 0, 0, 0);
    int gn = n0 + lr;
    uint4 bv = (gn < N) ? *(const uint4*)(Bt + (size_t)gn * K + k0 + lseg)
                        : make_uint4(0, 0, 0, 0);
    __syncthreads();
    *(uint4*)(&As[lr][lseg]) = av;
    *(uint4*)(&Bs[lr][lseg]) = bv;
    __syncthreads();
    short8 a0 = *(const short8*)(&As[wm + lrow][lq * 8]);
    short8 a1 = *(const short8*)(&As[wm + 16 + lrow][lq * 8]);
    short8 b0 = *(const short8*)(&Bs[wn + lrow][lq * 8]);
    short8 b1 = *(const short8*)(&Bs[wn + 16 + lrow][lq * 8]);
    acc[0][0] = __builtin_amdgcn_mfma_f32_16x16x32_bf16(a0, b0, acc[0][0], 0, 0, 0);
    acc[0][1] = __builtin_amdgcn_mfma_f32_16x16x32_bf16(a0, b1, acc[0][1], 0, 0, 0);
    acc[1][0] = __builtin_amdgcn_mfma_f32_16x16x32_bf16(a1, b0, acc[1][0], 0, 0, 0);
    acc[1][1] = __builtin_amdgcn_mfma_f32_16x16x32_bf16(a1, b1, acc[1][1], 0, 0, 0);
  }
  for (int tm = 0; tm < 2; tm++)
    for (int tn = 0; tn < 2; tn++)
      for (int r = 0; r < 4; r++) {
        int ml = wm + tm * 16 + lq * 4 + r;
        int nl = wn + tn * 16 + lrow;
        int gm = m0 + ml, gn = n0 + nl;
        if (gm >= M || gn >= N) continue;
        float val = acc[tm][tn][r] + bias[gn];
        if constexpr (MODE == 0) {
          int b = gm / Sn, s = gm % Sn;
          int h = gn >> 6, dh = gn & 63;
          Cb[(((size_t)b * Hn + h) * Sn + s) * DHn + dh] = f2bf(val);
        } else if constexpr (MODE == 1) {
          size_t o = (size_t)gm * N + gn;
          Cf[o] = val + res[o];
        } else if constexpr (MODE == 2) {
          float gl = 0.5f * val * (1.f + erff(val * 0.70710678118654752f));
          Cb[(size_t)gm * N + gn] = f2bf(gl);
        } else if constexpr (MODE == 3) {
          int b = gm / NPATCH, pi = gm % NPATCH;
          Cf[((size_t)b * Sn + 1 + pi) * Dn + gn] =
              val + res[(size_t)(1 + pi) * Dn + gn];
        } else {
          Cf[(size_t)gm * N + gn] = val;
        }
      }
}

// ---- attention: q,k,v bf16 [B][H][S][64] -> out bf16 [B][S][H*64] ----
#define SPAD 66
__global__ __launch_bounds__(256) void attention_k(
    const unsigned short* __restrict__ q, const unsigned short* __restrict__ k,
    const unsigned short* __restrict__ v, unsigned short* __restrict__ out) {
  int bh = blockIdx.x, b = bh / Hn, h = bh % Hn;
  const unsigned short* qp = q + (size_t)bh * Sn * DHn;
  const unsigned short* kp = k + (size_t)bh * Sn * DHn;
  const unsigned short* vp = v + (size_t)bh * Sn * DHn;
  __shared__ unsigned short kl[Sn][SPAD];
  __shared__ unsigned short vl[Sn][SPAD];
  __shared__ float qf[DHn];
  __shared__ float pl[256];
  __shared__ float redm[4], reds[4];
  __shared__ float oacc[4][DHn];
  int t = threadIdx.x, lane = t & 63, wid = t >> 6;
  for (int i = t; i < Sn * DHn; i += 256) {
    int r = i >> 6, c = i & 63;
    kl[r][c] = kp[i];
    vl[r][c] = vp[i];
  }
  __syncthreads();
  for (int s = 0; s < Sn; s++) {
    if (t < DHn) qf[t] = bf2f(qp[s * DHn + t]);
    __syncthreads();
    float sc = -1e30f;
    if (t < Sn) {
      float dot = 0.f;
      for (int d = 0; d < DHn; d++) dot += qf[d] * bf2f(kl[t][d]);
      sc = dot * 0.125f;
    }
    float wm_ = sc;
    for (int off = 32; off > 0; off >>= 1) wm_ = fmaxf(wm_, __shfl_xor(wm_, off, 64));
    if (lane == 0) redm[wid] = wm_;
    __syncthreads();
    float mx = fmaxf(fmaxf(redm[0], redm[1]), fmaxf(redm[2], redm[3]));
    float p = (t < Sn) ? __expf(sc - mx) : 0.f;
    pl[t] = p;
    float ws = p;
    for (int off = 32; off > 0; off >>= 1) ws += __shfl_xor(ws, off, 64);
    if (lane == 0) reds[wid] = ws;
    __syncthreads();
    float denom = reds[0] + reds[1] + reds[2] + reds[3];
    int d2 = t & 63, chunk = t >> 6;
    float acc = 0.f;
    for (int j = chunk; j < Sn; j += 4) acc += pl[j] * bf2f(vl[j][d2]);
    oacc[chunk][d2] = acc;
    __syncthreads();
    if (t < DHn) {
      float o = (oacc[0][t] + oacc[1][t] + oacc[2][t] + oacc[3][t]) / denom;
      out[((size_t)b * Sn + s) * Dn + h * DHn + t] = f2bf(o);
    }
    __syncthreads();
  }
}

extern "C" void kernel_launch(void* const* d_in, const int* in_sizes, int n_in,
                              void* d_out, int out_size, void* d_ws, size_t ws_size,
                              hipStream_t stream) {
  const float* X       = (const float*)d_in[0];
  const float* patch_w = (const float*)d_in[1];
  const float* patch_b = (const float*)d_in[2];
  const float* cls_tok = (const float*)d_in[3];
  const float* pos_emb = (const float*)d_in[4];
  const float* ln1_g = (const float*)d_in[5];
  const float* ln1_b = (const float*)d_in[6];
  const float* Wq = (const float*)d_in[7];
  const float* bq = (const float*)d_in[8];
  const float* Wk = (const float*)d_in[9];
  const float* bk = (const float*)d_in[10];
  const float* Wv = (const float*)d_in[11];
  const float* bv = (const float*)d_in[12];
  const float* Wo = (const float*)d_in[13];
  const float* bo = (const float*)d_in[14];
  const float* ln2_g = (const float*)d_in[15];
  const float* ln2_b = (const float*)d_in[16];
  const float* Wf1 = (const float*)d_in[17];
  const float* bf1 = (const float*)d_in[18];
  const float* Wf2 = (const float*)d_in[19];
  const float* bf2 = (const float*)d_in[20];
  const float* lnf_g = (const float*)d_in[21];
  const float* lnf_b = (const float*)d_in[22];
  const float* head_w = (const float*)d_in[23];
  const float* head_b = (const float*)d_in[24];
  float* out = (float*)d_out;

  char* base = (char*)d_ws;
  size_t off = 0;
  auto alloc = [&](size_t bytes) -> void* {
    void* p = base + off;
    off += (bytes + 255) & ~(size_t)255;
    return p;
  };
  unsigned short* wq_t  = (unsigned short*)alloc((size_t)Dn * Dn * 2);
  unsigned short* wk_t  = (unsigned short*)alloc((size_t)Dn * Dn * 2);
  unsigned short* wv_t  = (unsigned short*)alloc((size_t)Dn * Dn * 2);
  unsigned short* wo_t  = (unsigned short*)alloc((size_t)Dn * Dn * 2);
  unsigned short* wf1_t = (unsigned short*)alloc((size_t)Dn * Fn * 2);
  unsigned short* wf2_t = (unsigned short*)alloc((size_t)Dn * Fn * 2);
  unsigned short* pw_bf = (unsigned short*)alloc((size_t)Dn * Dn * 2);
  unsigned short* hw_t  = (unsigned short*)alloc((size_t)NCLSn * Dn * 2);
  unsigned short* im2c  = (unsigned short*)alloc((size_t)Bn * NPATCH * Dn * 2);
  float*          x     = (float*)alloc((size_t)MTOK * Dn * 4);
  unsigned short* h_bf  = (unsigned short*)alloc((size_t)MTOK * Dn * 2);
  unsigned short* qb    = (unsigned short*)alloc((size_t)MTOK * Dn * 2);
  unsigned short* kb    = (unsigned short*)alloc((size_t)MTOK * Dn * 2);
  unsigned short* vb    = (unsigned short*)alloc((size_t)MTOK * Dn * 2);
  unsigned short* atob  = (unsigned short*)alloc((size_t)MTOK * Dn * 2);
  unsigned short* gel   = (unsigned short*)alloc((size_t)MTOK * Fn * 2);
  unsigned short* clsb  = (unsigned short*)alloc((size_t)Bn * Dn * 2);
  (void)ws_size; (void)in_sizes; (void)n_in; (void)out_size;

  dim3 tb(32, 8);
  auto tgrid = [](int rows, int cols) { return dim3((cols + 31) / 32, (rows + 31) / 32); };
  auto ggrid = [](int M, int N) { return dim3((M + 63) / 64, (N + 63) / 64); };

  // prologue
  cast_bf<<<(Dn * Dn + 255) / 256, 256, 0, stream>>>(patch_w, pw_bf, Dn * Dn);
  transpose_cast<<<tgrid(Dn, NCLSn), tb, 0, stream>>>(head_w, hw_t, Dn, NCLSn);
  im2col_patches<<<(Bn * NPATCH * Dn + 255) / 256, 256, 0, stream>>>(X, im2c);
  init_cls<<<(Bn * Dn + 255) / 256, 256, 0, stream>>>(cls_tok, pos_emb, x);
  gemm64<3><<<ggrid(Bn * NPATCH, Dn), 256, 0, stream>>>(
      im2c, pw_bf, patch_b, pos_emb, x, nullptr, Bn * NPATCH, Dn, Dn);

  for (int l = 0; l < Ln; l++) {
    const size_t wo_off = (size_t)l * Dn * Dn;
    const size_t wf_off = (size_t)l * Dn * Fn;
    transpose_cast<<<tgrid(Dn, Dn), tb, 0, stream>>>(Wq + wo_off, wq_t, Dn, Dn);
    transpose_cast<<<tgrid(Dn, Dn), tb, 0, stream>>>(Wk + wo_off, wk_t, Dn, Dn);
    transpose_cast<<<tgrid(Dn, Dn), tb, 0, stream>>>(Wv + wo_off, wv_t, Dn, Dn);
    transpose_cast<<<tgrid(Dn, Dn), tb, 0, stream>>>(Wo + wo_off, wo_t, Dn, Dn);
    transpose_cast<<<tgrid(Dn, Fn), tb, 0, stream>>>(Wf1 + wf_off, wf1_t, Dn, Fn);
    transpose_cast<<<tgrid(Fn, Dn), tb, 0, stream>>>(Wf2 + wf_off, wf2_t, Fn, Dn);

    layernorm_k<<<MTOK, 256, 0, stream>>>(x, Dn, ln1_g + (size_t)l * Dn,
                                          ln1_b + (size_t)l * Dn, h_bf);
    gemm64<0><<<ggrid(MTOK, Dn), 256, 0, stream>>>(
        h_bf, wq_t, bq + (size_t)l * Dn, nullptr, nullptr, qb, MTOK, Dn, Dn);
    gemm64<0><<<ggrid(MTOK, Dn), 256, 0, stream>>>(
        h_bf, wk_t, bk + (size_t)l * Dn, nullptr, nullptr, kb, MTOK, Dn, Dn);
    gemm64<0><<<ggrid(MTOK, Dn), 256, 0, stream>>>(
        h_bf, wv_t, bv + (size_t)l * Dn, nullptr, nullptr, vb, MTOK, Dn, Dn);
    attention_k<<<Bn * Hn, 256, 0, stream>>>(qb, kb, vb, atob);
    gemm64<1><<<ggrid(MTOK, Dn), 256, 0, stream>>>(
        atob, wo_t, bo + (size_t)l * Dn, x, x, nullptr, MTOK, Dn, Dn);
    layernorm_k<<<MTOK, 256, 0, stream>>>(x, Dn, ln2_g + (size_t)l * Dn,
                                          ln2_b + (size_t)l * Dn, h_bf);
    gemm64<2><<<ggrid(MTOK, Fn), 256, 0, stream>>>(
        h_bf, wf1_t, bf1 + (size_t)l * Fn, nullptr, nullptr, gel, MTOK, Fn, Dn);
    gemm64<1><<<ggrid(MTOK, Dn), 256, 0, stream>>>(
        gel, wf2_t, bf2 + (size_t)l * Dn, x, x, nullptr, MTOK, Dn, Fn);
  }

  layernorm_k<<<Bn, 256, 0, stream>>>(x, Sn * Dn, lnf_g, lnf_b, clsb);
  gemm64<4><<<ggrid(Bn, NCLSn), 256, 0, stream>>>(
      clsb, hw_t, head_b, nullptr, out, nullptr, Bn, NCLSn, Dn);
}

// Round 2
// 4598.224 us; speedup vs baseline: 2.8246x; 2.8246x over previous
//
#include <hip/hip_runtime.h>
#include <math.h>

// ---- problem constants ----
#define Bn 32
#define Sn 197
#define Dn 768
#define Hn 12
#define DHn 64
#define Fn 3072
#define Ln 12
#define NPATCH 196
#define NCLSn 1000
#define MTOK (Bn * Sn)   // 6304

typedef __attribute__((ext_vector_type(8))) short short8;
typedef __attribute__((ext_vector_type(4))) float f32x4;

__device__ __forceinline__ unsigned short f2bf(float f) {
  union { float f; unsigned int u; } v; v.f = f;
  unsigned int r = v.u + 0x7fffu + ((v.u >> 16) & 1u);
  return (unsigned short)(r >> 16);
}
__device__ __forceinline__ float bf2f(unsigned short h) {
  union { unsigned int u; float f; } v; v.u = ((unsigned int)h) << 16;
  return v.f;
}

// ---- transpose + cast fp32[rows][cols] -> bf16[cols][rows] ----
__global__ __launch_bounds__(256) void transpose_cast(
    const float* __restrict__ in, unsigned short* __restrict__ out,
    int rows, int cols) {
  __shared__ float tile[32][33];
  int c0 = blockIdx.x * 32, r0 = blockIdx.y * 32;
  int tx = threadIdx.x, ty = threadIdx.y;
  for (int i = 0; i < 32; i += 8) {
    int r = r0 + ty + i, c = c0 + tx;
    tile[ty + i][tx] = (r < rows && c < cols) ? in[(size_t)r * cols + c] : 0.f;
  }
  __syncthreads();
  for (int i = 0; i < 32; i += 8) {
    int c = c0 + ty + i, r = r0 + tx;
    if (c < cols && r < rows)
      out[(size_t)c * rows + r] = f2bf(tile[tx][ty + i]);
  }
}

// ---- plain cast fp32 -> bf16 ----
__global__ __launch_bounds__(256) void cast_bf(
    const float* __restrict__ in, unsigned short* __restrict__ out, int n) {
  int i = blockIdx.x * 256 + threadIdx.x;
  if (i < n) out[i] = f2bf(in[i]);
}

// ---- im2col: X[B,3,224,224] -> A[b*196+hp*14+wp][c*256+p*16+q] bf16 ----
__global__ __launch_bounds__(256) void im2col_patches(
    const float* __restrict__ X, unsigned short* __restrict__ A) {
  int idx = blockIdx.x * 256 + threadIdx.x;
  if (idx >= NPATCH * Bn * Dn) return;
  int col = idx % Dn, row = idx / Dn;
  int b = row / NPATCH, pi = row % NPATCH;
  int hp = pi / 14, wp = pi % 14;
  int c = col >> 8, r2 = col & 255, p = r2 >> 4, q = r2 & 15;
  A[idx] = f2bf(X[(((size_t)b * 3 + c) * 224 + hp * 16 + p) * 224 + wp * 16 + q]);
}

// ---- x[b][0][:] = cls_token + pos_emb[0] ----
__global__ __launch_bounds__(256) void init_cls(
    const float* __restrict__ cls_tok, const float* __restrict__ pos_emb,
    float* __restrict__ x) {
  int i = blockIdx.x * 256 + threadIdx.x;
  if (i >= Bn * Dn) return;
  int b = i / Dn, d = i % Dn;
  x[(size_t)b * Sn * Dn + d] = cls_tok[d] + pos_emb[d];
}

// ---- LayerNorm over D=768; out bf16 ----
__global__ __launch_bounds__(256) void layernorm_k(
    const float* __restrict__ x, int row_stride,
    const float* __restrict__ g, const float* __restrict__ b,
    unsigned short* __restrict__ out) {
  int row = blockIdx.x, t = threadIdx.x;
  const float* xr = x + (size_t)row * row_stride;
  float v0 = xr[t], v1 = xr[t + 256], v2 = xr[t + 512];
  float s = v0 + v1 + v2;
  __shared__ float red[4];
  int lane = t & 63, wid = t >> 6;
  for (int off = 32; off > 0; off >>= 1) s += __shfl_xor(s, off, 64);
  if (lane == 0) red[wid] = s;
  __syncthreads();
  float mean = (red[0] + red[1] + red[2] + red[3]) * (1.f / 768.f);
  __syncthreads();
  float d0 = v0 - mean, d1 = v1 - mean, d2 = v2 - mean;
  float q = d0 * d0 + d1 * d1 + d2 * d2;
  for (int off = 32; off > 0; off >>= 1) q += __shfl_xor(q, off, 64);
  if (lane == 0) red[wid] = q;
  __syncthreads();
  float var = (red[0] + red[1] + red[2] + red[3]) * (1.f / 768.f);
  float rstd = rsqrtf(var + 1e-5f);
  size_t o = (size_t)row * Dn;
  out[o + t]       = f2bf(d0 * rstd * g[t]       + b[t]);
  out[o + t + 256] = f2bf(d1 * rstd * g[t + 256] + b[t + 256]);
  out[o + t + 512] = f2bf(d2 * rstd * g[t + 512] + b[t + 512]);
}

// ---- MFMA GEMM: C[M][N] = A[M][K](bf16) * Bt[N][K](bf16)^T, fused epilogues ----
// MODE 0: out bf16 qkv [B][H][S][DH]        (bias)
// MODE 1: out fp32 [M][N] = acc+bias+res    (residual add, in-place on x ok)
// MODE 2: out bf16 [M][N] = gelu(acc+bias)
// MODE 3: patch: out fp32 x[b][1+pi][n] = acc+bias+pos_emb[(1+pi)*D+n]
// MODE 4: out fp32 [M][N] = acc+bias
template <int MODE>
__global__ __launch_bounds__(256) void gemm64(
    const unsigned short* __restrict__ A, const unsigned short* __restrict__ Bt,
    const float* __restrict__ bias, const float* __restrict__ res,
    float* __restrict__ Cf, unsigned short* __restrict__ Cb,
    int M, int N, int K) {
  __shared__ unsigned short As[64][32];
  __shared__ unsigned short Bs[64][32];
  int m0 = blockIdx.x * 64, n0 = blockIdx.y * 64;
  int tid = threadIdx.x;
  int wid = tid >> 6, lane = tid & 63;
  int wm = (wid >> 1) * 32, wn = (wid & 1) * 32;
  int lrow = lane & 15, lq = lane >> 4;
  int lr = tid >> 2, lseg = (tid & 3) * 8;
  f32x4 acc[2][2] = {};
  for (int k0 = 0; k0 < K; k0 += 32) {
    int gm = m0 + lr;
    uint4 av = (gm < M) ? *(const uint4*)(A + (size_t)gm * K + k0 + lseg)
                        : make_uint4(0, 0, 0, 0);
    int gn = n0 + lr;
    uint4 bv = (gn < N) ? *(const uint4*)(Bt + (size_t)gn * K + k0 + lseg)
                        : make_uint4(0, 0, 0, 0);
    __syncthreads();
    *(uint4*)(&As[lr][lseg]) = av;
    *(uint4*)(&Bs[lr][lseg]) = bv;
    __syncthreads();
    short8 a0 = *(const short8*)(&As[wm + lrow][lq * 8]);
    short8 a1 = *(const short8*)(&As[wm + 16 + lrow][lq * 8]);
    short8 b0 = *(const short8*)(&Bs[wn + lrow][lq * 8]);
    short8 b1 = *(const short8*)(&Bs[wn + 16 + lrow][lq * 8]);
    acc[0][0] = __builtin_amdgcn_mfma_f32_16x16x32_bf16(a0, b0, acc[0][0], 0, 0, 0);
    acc[0][1] = __builtin_amdgcn_mfma_f32_16x16x32_bf16(a0, b1, acc[0][1], 0, 0, 0);
    acc[1][0] = __builtin_amdgcn_mfma_f32_16x16x32_bf16(a1, b0, acc[1][0], 0, 0, 0);
    acc[1][1] = __builtin_amdgcn_mfma_f32_16x16x32_bf16(a1, b1, acc[1][1], 0, 0, 0);
  }
  for (int tm = 0; tm < 2; tm++)
    for (int tn = 0; tn < 2; tn++)
      for (int r = 0; r < 4; r++) {
        int ml = wm + tm * 16 + lq * 4 + r;
        int nl = wn + tn * 16 + lrow;
        int gm = m0 + ml, gn = n0 + nl;
        if (gm >= M || gn >= N) continue;
        float val = acc[tm][tn][r] + bias[gn];
        if constexpr (MODE == 0) {
          int b = gm / Sn, s = gm % Sn;
          int h = gn >> 6, dh = gn & 63;
          Cb[(((size_t)b * Hn + h) * Sn + s) * DHn + dh] = f2bf(val);
        } else if constexpr (MODE == 1) {
          size_t o = (size_t)gm * N + gn;
          Cf[o] = val + res[o];
        } else if constexpr (MODE == 2) {
          float gl = 0.5f * val * (1.f + erff(val * 0.70710678118654752f));
          Cb[(size_t)gm * N + gn] = f2bf(gl);
        } else if constexpr (MODE == 3) {
          int b = gm / NPATCH, pi = gm % NPATCH;
          Cf[((size_t)b * Sn + 1 + pi) * Dn + gn] =
              val + res[(size_t)(1 + pi) * Dn + gn];
        } else {
          Cf[(size_t)gm * N + gn] = val;
        }
      }
}

// ---- MFMA flash-style attention ----
// q,k,v bf16 [B][H][S][64] -> out bf16 [B][S][H*64]
// grid = B*H blocks, 256 threads (4 waves). Each wave owns query tiles
// {wid, wid+4, wid+8, ...} of 16 queries. QK^T and PV via mfma 16x16x32.
// Q/K fragments load straight from global (layout matches A/B^T fragments).
// V staged transposed in LDS; P round-trips via per-wave LDS (C->A layout).
#define QT 16
#define NKT 13        // ceil(197/16)
#define PJ 232        // padded j extent: >= 7*32=224, stride 232 elems
                      //   = 116 dwords -> gcd(116,32)=4 -> even 4-bank spread
__global__ __launch_bounds__(256) void attn_mfma(
    const unsigned short* __restrict__ q, const unsigned short* __restrict__ k,
    const unsigned short* __restrict__ v, unsigned short* __restrict__ out) {
  int bh = blockIdx.x, b = bh / Hn, h = bh % Hn;
  const unsigned short* qp = q + (size_t)bh * Sn * DHn;
  const unsigned short* kp = k + (size_t)bh * Sn * DHn;
  const unsigned short* vp = v + (size_t)bh * Sn * DHn;
  __shared__ unsigned short Vt[DHn][PJ];      // 64 x 232 bf16 = 29 KB
  __shared__ unsigned short Pl[4][QT][PJ];    // per-wave P,   = 29 KB
  int t = threadIdx.x, lane = t & 63, wid = t >> 6;
  int col = lane & 15, quad = lane >> 4;

  // stage V transposed (coalesced global reads, 8-way-conflict LDS writes)
  for (int i = t; i < Sn * DHn; i += 256) {
    int j = i >> 6, d = i & 63;
    Vt[d][j] = vp[i];
  }
  // zero the j-tail of Vt (j = 197..231) so PV's padded chunks are clean
  for (int i = t; i < DHn * (PJ - Sn); i += 256) {
    int d = i / (PJ - Sn), j = Sn + i % (PJ - Sn);
    Vt[d][j] = 0;
  }
  // zero the j-tail of this wave's P (cols 208..231 never written in-loop)
  for (int i = lane; i < QT * (PJ - NKT * 16); i += 64) {
    int r = i / (PJ - NKT * 16), c = NKT * 16 + i % (PJ - NKT * 16);
    Pl[wid][r][c] = 0;
  }
  __syncthreads();

  for (int qt = wid; qt < NKT; qt += 4) {
    int q0 = qt * QT;
    int qrow = q0 + col;
    int qc = (qrow < Sn) ? qrow : (Sn - 1);
    short8 qa0 = *(const short8*)(qp + (size_t)qc * DHn + quad * 8);
    short8 qa1 = *(const short8*)(qp + (size_t)qc * DHn + 32 + quad * 8);

    // ---- scores: 13 C-fragments, keys kt*16+col, rows q0+quad*4+r ----
    f32x4 sc[NKT];
    for (int kt = 0; kt < NKT; kt++) {
      int krow = kt * QT + col;
      int kc = (krow < Sn) ? krow : (Sn - 1);
      short8 kb0 = *(const short8*)(kp + (size_t)kc * DHn + quad * 8);
      short8 kb1 = *(const short8*)(kp + (size_t)kc * DHn + 32 + quad * 8);
      f32x4 c = {};
      c = __builtin_amdgcn_mfma_f32_16x16x32_bf16(qa0, kb0, c, 0, 0, 0);
      c = __builtin_amdgcn_mfma_f32_16x16x32_bf16(qa1, kb1, c, 0, 0, 0);
      if (krow >= Sn)
        for (int r = 0; r < 4; r++) c[r] = -1e30f;
      sc[kt] = c;
    }

    // ---- softmax per row (rows live on the 16 lanes of each quad) ----
    for (int r = 0; r < 4; r++) {
      float m = -1e30f;
      for (int kt = 0; kt < NKT; kt++) m = fmaxf(m, sc[kt][r]);
      for (int off = 1; off < 16; off <<= 1) m = fmaxf(m, __shfl_xor(m, off, 64));
      float s = 0.f;
      for (int kt = 0; kt < NKT; kt++) {
        float e = __expf((sc[kt][r] - m) * 0.125f);
        sc[kt][r] = e;
        s += e;
      }
      for (int off = 1; off < 16; off <<= 1) s += __shfl_xor(s, off, 64);
      float inv = 1.f / s;
      int row = quad * 4 + r;
      for (int kt = 0; kt < NKT; kt++)
        Pl[wid][row][kt * 16 + col] = f2bf(sc[kt][r] * inv);
    }

    // ---- PV: out[16q x 64d] over 7 j-chunks of 32 ----
    f32x4 o[4] = {};
    for (int jc = 0; jc < 7; jc++) {
      short8 pa = *(const short8*)(&Pl[wid][col][jc * 32 + quad * 8]);
      for (int dt = 0; dt < 4; dt++) {
        short8 vb = *(const short8*)(&Vt[dt * 16 + col][jc * 32 + quad * 8]);
        o[dt] = __builtin_amdgcn_mfma_f32_16x16x32_bf16(pa, vb, o[dt], 0, 0, 0);
      }
    }

    // ---- write out[b][s][h*64+d]; C layout: col=d (lane&15), row=quad*4+r
    for (int dt = 0; dt < 4; dt++)
      for (int r = 0; r < 4; r++) {
        int qq = q0 + quad * 4 + r;
        if (qq < Sn)
          out[((size_t)b * Sn + qq) * Dn + h * DHn + dt * 16 + col] =
              f2bf(o[dt][r]);
      }
  }
}

extern "C" void kernel_launch(void* const* d_in, const int* in_sizes, int n_in,
                              void* d_out, int out_size, void* d_ws, size_t ws_size,
                              hipStream_t stream) {
  const float* X       = (const float*)d_in[0];
  const float* patch_w = (const float*)d_in[1];
  const float* patch_b = (const float*)d_in[2];
  const float* cls_tok = (const float*)d_in[3];
  const float* pos_emb = (const float*)d_in[4];
  const float* ln1_g = (const float*)d_in[5];
  const float* ln1_b = (const float*)d_in[6];
  const float* Wq = (const float*)d_in[7];
  const float* bq = (const float*)d_in[8];
  const float* Wk = (const float*)d_in[9];
  const float* bk = (const float*)d_in[10];
  const float* Wv = (const float*)d_in[11];
  const float* bv = (const float*)d_in[12];
  const float* Wo = (const float*)d_in[13];
  const float* bo = (const float*)d_in[14];
  const float* ln2_g = (const float*)d_in[15];
  const float* ln2_b = (const float*)d_in[16];
  const float* Wf1 = (const float*)d_in[17];
  const float* bf1 = (const float*)d_in[18];
  const float* Wf2 = (const float*)d_in[19];
  const float* bf2 = (const float*)d_in[20];
  const float* lnf_g = (const float*)d_in[21];
  const float* lnf_b = (const float*)d_in[22];
  const float* head_w = (const float*)d_in[23];
  const float* head_b = (const float*)d_in[24];
  float* out = (float*)d_out;

  char* base = (char*)d_ws;
  size_t off = 0;
  auto alloc = [&](size_t bytes) -> void* {
    void* p = base + off;
    off += (bytes + 255) & ~(size_t)255;
    return p;
  };
  unsigned short* wq_t  = (unsigned short*)alloc((size_t)Dn * Dn * 2);
  unsigned short* wk_t  = (unsigned short*)alloc((size_t)Dn * Dn * 2);
  unsigned short* wv_t  = (unsigned short*)alloc((size_t)Dn * Dn * 2);
  unsigned short* wo_t  = (unsigned short*)alloc((size_t)Dn * Dn * 2);
  unsigned short* wf1_t = (unsigned short*)alloc((size_t)Dn * Fn * 2);
  unsigned short* wf2_t = (unsigned short*)alloc((size_t)Dn * Fn * 2);
  unsigned short* pw_bf = (unsigned short*)alloc((size_t)Dn * Dn * 2);
  unsigned short* hw_t  = (unsigned short*)alloc((size_t)NCLSn * Dn * 2);
  unsigned short* im2c  = (unsigned short*)alloc((size_t)Bn * NPATCH * Dn * 2);
  float*          x     = (float*)alloc((size_t)MTOK * Dn * 4);
  unsigned short* h_bf  = (unsigned short*)alloc((size_t)MTOK * Dn * 2);
  unsigned short* qb    = (unsigned short*)alloc((size_t)MTOK * Dn * 2);
  unsigned short* kb    = (unsigned short*)alloc((size_t)MTOK * Dn * 2);
  unsigned short* vb    = (unsigned short*)alloc((size_t)MTOK * Dn * 2);
  unsigned short* atob  = (unsigned short*)alloc((size_t)MTOK * Dn * 2);
  unsigned short* gel   = (unsigned short*)alloc((size_t)MTOK * Fn * 2);
  unsigned short* clsb  = (unsigned short*)alloc((size_t)Bn * Dn * 2);
  (void)ws_size; (void)in_sizes; (void)n_in; (void)out_size;

  dim3 tb(32, 8);
  auto tgrid = [](int rows, int cols) { return dim3((cols + 31) / 32, (rows + 31) / 32); };
  auto ggrid = [](int M, int N) { return dim3((M + 63) / 64, (N + 63) / 64); };

  // prologue
  cast_bf<<<(Dn * Dn + 255) / 256, 256, 0, stream>>>(patch_w, pw_bf, Dn * Dn);
  transpose_cast<<<tgrid(Dn, NCLSn), tb, 0, stream>>>(head_w, hw_t, Dn, NCLSn);
  im2col_patches<<<(Bn * NPATCH * Dn + 255) / 256, 256, 0, stream>>>(X, im2c);
  init_cls<<<(Bn * Dn + 255) / 256, 256, 0, stream>>>(cls_tok, pos_emb, x);
  gemm64<3><<<ggrid(Bn * NPATCH, Dn), 256, 0, stream>>>(
      im2c, pw_bf, patch_b, pos_emb, x, nullptr, Bn * NPATCH, Dn, Dn);

  for (int l = 0; l < Ln; l++) {
    const size_t wo_off = (size_t)l * Dn * Dn;
    const size_t wf_off = (size_t)l * Dn * Fn;
    transpose_cast<<<tgrid(Dn, Dn), tb, 0, stream>>>(Wq + wo_off, wq_t, Dn, Dn);
    transpose_cast<<<tgrid(Dn, Dn), tb, 0, stream>>>(Wk + wo_off, wk_t, Dn, Dn);
    transpose_cast<<<tgrid(Dn, Dn), tb, 0, stream>>>(Wv + wo_off, wv_t, Dn, Dn);
    transpose_cast<<<tgrid(Dn, Dn), tb, 0, stream>>>(Wo + wo_off, wo_t, Dn, Dn);
    transpose_cast<<<tgrid(Dn, Fn), tb, 0, stream>>>(Wf1 + wf_off, wf1_t, Dn, Fn);
    transpose_cast<<<tgrid(Fn, Dn), tb, 0, stream>>>(Wf2 + wf_off, wf2_t, Fn, Dn);

    layernorm_k<<<MTOK, 256, 0, stream>>>(x, Dn, ln1_g + (size_t)l * Dn,
                                          ln1_b + (size_t)l * Dn, h_bf);
    gemm64<0><<<ggrid(MTOK, Dn), 256, 0, stream>>>(
        h_bf, wq_t, bq + (size_t)l * Dn, nullptr, nullptr, qb, MTOK, Dn, Dn);
    gemm64<0><<<ggrid(MTOK, Dn), 256, 0, stream>>>(
        h_bf, wk_t, bk + (size_t)l * Dn, nullptr, nullptr, kb, MTOK, Dn, Dn);
    gemm64<0><<<ggrid(MTOK, Dn), 256, 0, stream>>>(
        h_bf, wv_t, bv + (size_t)l * Dn, nullptr, nullptr, vb, MTOK, Dn, Dn);
    attn_mfma<<<Bn * Hn, 256, 0, stream>>>(qb, kb, vb, atob);
    gemm64<1><<<ggrid(MTOK, Dn), 256, 0, stream>>>(
        atob, wo_t, bo + (size_t)l * Dn, x, x, nullptr, MTOK, Dn, Dn);
    layernorm_k<<<MTOK, 256, 0, stream>>>(x, Dn, ln2_g + (size_t)l * Dn,
                                          ln2_b + (size_t)l * Dn, h_bf);
    gemm64<2><<<ggrid(MTOK, Fn), 256, 0, stream>>>(
        h_bf, wf1_t, bf1 + (size_t)l * Fn, nullptr, nullptr, gel, MTOK, Fn, Dn);
    gemm64<1><<<ggrid(MTOK, Dn), 256, 0, stream>>>(
        gel, wf2_t, bf2 + (size_t)l * Dn, x, x, nullptr, MTOK, Dn, Fn);
  }

  layernorm_k<<<Bn, 256, 0, stream>>>(x, Sn * Dn, lnf_g, lnf_b, clsb);
  gemm64<4><<<ggrid(Bn, NCLSn), 256, 0, stream>>>(
      clsb, hw_t, head_b, nullptr, out, nullptr, Bn, NCLSn, Dn);
}